// Round 6
// baseline (2631.633 us; speedup 1.0000x reference)
//
#include <hip/hip_runtime.h>
#include <math.h>
#include <stdint.h>

#define B_ 8
#define N_ 2048
#define K_ 20
#define EPSV 1e-5f
#define SLOPEV 0.2f

typedef __bf16 bf16;
typedef __attribute__((ext_vector_type(8))) __bf16 bf16x8;
typedef __attribute__((ext_vector_type(4))) float f32x4;

static __device__ __forceinline__ float leakyf(float v){ return v >= 0.f ? v : SLOPEV*v; }

// async global->LDS, 16B per lane; lds dest = uniform base + lane*16
static __device__ __forceinline__ void gload_lds16(const void* g, void* l){
  __builtin_amdgcn_global_load_lds((const __attribute__((address_space(1))) unsigned int*)g,
                                   (__attribute__((address_space(3))) unsigned int*)l,
                                   16, 0, 0);
}

// ---- stage-1 prep: x (B,3,N) -> Xhi/Xmd/Xlo (B*N,32) bf16 (exact 3-split) + xx + x0t ----
__global__ void k_prep_x1(const float* __restrict__ x, bf16* __restrict__ Xhi,
                          bf16* __restrict__ Xmd, bf16* __restrict__ Xlo,
                          float* __restrict__ xx, float* __restrict__ x0t){
  int id = blockIdx.x*256 + threadIdx.x;
  if (id >= B_*N_) return;
  int b = id / N_, n = id % N_;
  float s = 0.f;
  #pragma unroll
  for (int c = 0; c < 32; ++c){
    float v = (c < 3) ? x[((size_t)b*3 + c)*N_ + n] : 0.f;
    bf16 h = (bf16)v;
    float r1 = v - (float)h;
    bf16 m = (bf16)r1;
    float r2 = r1 - (float)m;
    Xhi[(size_t)id*32 + c] = h;
    Xmd[(size_t)id*32 + c] = m;
    Xlo[(size_t)id*32 + c] = (bf16)r2;   // exact: residual has <=8 mantissa bits
    s = fmaf(v, v, s);
    if (c < 8) x0t[(size_t)id*8 + c] = v;
  }
  xx[id] = s;
}

// ---- stage 2-4 prep: xc slice (ld 512) -> Xhi/Xmd/Xlo (B*N,Cin) + xx ----
__global__ void k_prep_xc(const float* __restrict__ X, int Cin, bf16* __restrict__ Xhi,
                          bf16* __restrict__ Xmd, bf16* __restrict__ Xlo,
                          float* __restrict__ xx){
  int id = blockIdx.x*256 + threadIdx.x;
  if (id >= B_*N_) return;
  const float* p = X + (size_t)id*512;
  float s = 0.f;
  for (int c = 0; c < Cin; ++c){
    float v = p[c];
    bf16 h = (bf16)v;
    float r1 = v - (float)h;
    bf16 m = (bf16)r1;
    float r2 = r1 - (float)m;
    Xhi[(size_t)id*Cin + c] = h;
    Xmd[(size_t)id*Cin + c] = m;
    Xlo[(size_t)id*Cin + c] = (bf16)r2;
    s = fmaf(v, v, s);
  }
  xx[id] = s;
}

// ---- Wa[o][c] = W[o][c]; Wd[o][c] = W[o][C+c]-W[o][c]  (fp32, ld C) ----
__global__ void k_prep_w(const float* __restrict__ W, float* __restrict__ Wa,
                         float* __restrict__ Wd, int O, int C){
  int id = blockIdx.x*256 + threadIdx.x;
  if (id >= O*C) return;
  int o = id / C, c = id % C;
  float a = W[(size_t)o*2*C + c];
  float d = W[(size_t)o*2*C + C + c];
  Wa[id] = a; Wd[id] = d - a;
}

// ---------------- small fp32 NT GEMM (64x64 tile) for O=64 u/v ----------------
#define BM 64
#define BN 64
#define BKT 16

__global__ __launch_bounds__(256)
void k_gemm_nt(const float* __restrict__ A, int lda, long sA,
               const float* __restrict__ Bm, int ldb, long sB,
               float* __restrict__ Cm, int ldc, long sC, int K){
  __shared__ float As[BKT][BM+4];
  __shared__ float Bs[BKT][BN+4];
  const int z = blockIdx.z;
  const float* Ab = A + (size_t)z*sA;
  const float* Bb = Bm + (size_t)z*sB;
  float* Cb = Cm + (size_t)z*sC;
  const int m0 = blockIdx.x*BM, n0 = blockIdx.y*BN;
  const int tid = threadIdx.x;
  const int tm = tid >> 4, tn = tid & 15;
  const int lm = tid >> 2, lk = (tid & 3)*4;
  float acc[4][4] = {};
  for (int k0 = 0; k0 < K; k0 += BKT){
    #pragma unroll
    for (int i = 0; i < 4; ++i){
      int kk = lk + i;
      As[kk][lm] = (k0+kk < K) ? Ab[(size_t)(m0+lm)*lda + k0+kk] : 0.f;
      Bs[kk][lm] = (k0+kk < K) ? Bb[(size_t)(n0+lm)*ldb + k0+kk] : 0.f;
    }
    __syncthreads();
    #pragma unroll
    for (int kk = 0; kk < BKT; ++kk){
      float a4[4], b4[4];
      *(float4*)a4 = *(const float4*)&As[kk][tm*4];
      *(float4*)b4 = *(const float4*)&Bs[kk][tn*4];
      #pragma unroll
      for (int i = 0; i < 4; ++i)
        #pragma unroll
        for (int j = 0; j < 4; ++j)
          acc[i][j] = fmaf(a4[i], b4[j], acc[i][j]);
    }
    __syncthreads();
  }
  #pragma unroll
  for (int i = 0; i < 4; ++i){
    int m = m0 + tm*4 + i;
    #pragma unroll
    for (int j = 0; j < 4; ++j)
      Cb[(size_t)m*ldc + n0 + tn*4 + j] = acc[i][j];
  }
}

// ---------------- fp32 NT GEMM: 128x128 tile, 8x8/thread, BK=8 (u/v O>=128, h5) ----------------
#define GBM 128
#define GBN 128
#define GBK 8

__global__ __launch_bounds__(256)
void k_gemm128(const float* __restrict__ A, int lda, long sA,
               const float* __restrict__ Bm, int ldb, long sB,
               float* __restrict__ Cm, int ldc, long sC, int K){
  __shared__ float As[GBK][GBM];
  __shared__ float Bs[GBK][GBN];
  const int z = blockIdx.z;
  const float* Ab = A + (size_t)z*sA;
  const float* Bb = Bm + (size_t)z*sB;
  float* Cb = Cm + (size_t)z*sC;
  const int m0 = blockIdx.x*GBM, n0 = blockIdx.y*GBN;
  const int t = threadIdx.x;
  const int tm = t >> 4, tn = t & 15;
  const int sr = t >> 1;
  const int sk = (t & 1) * 4;
  float acc[8][8] = {};
  for (int k0 = 0; k0 < K; k0 += GBK){
    float4 av = *(const float4*)&Ab[(size_t)(m0+sr)*lda + k0 + sk];
    float4 bv = *(const float4*)&Bb[(size_t)(n0+sr)*ldb + k0 + sk];
    __syncthreads();
    As[sk+0][sr]=av.x; As[sk+1][sr]=av.y; As[sk+2][sr]=av.z; As[sk+3][sr]=av.w;
    Bs[sk+0][sr]=bv.x; Bs[sk+1][sr]=bv.y; Bs[sk+2][sr]=bv.z; Bs[sk+3][sr]=bv.w;
    __syncthreads();
    #pragma unroll
    for (int kk = 0; kk < GBK; ++kk){
      float a[8], b[8];
      *(float4*)&a[0] = *(const float4*)&As[kk][tm*4];
      *(float4*)&a[4] = *(const float4*)&As[kk][64 + tm*4];
      *(float4*)&b[0] = *(const float4*)&Bs[kk][tn*4];
      *(float4*)&b[4] = *(const float4*)&Bs[kk][64 + tn*4];
      #pragma unroll
      for (int i = 0; i < 8; ++i)
        #pragma unroll
        for (int j = 0; j < 8; ++j)
          acc[i][j] = fmaf(a[i], b[j], acc[i][j]);
    }
  }
  #pragma unroll
  for (int i = 0; i < 8; ++i){
    int m = m0 + ((i<4) ? (tm*4+i) : (64+tm*4+i-4));
    float4 v0, v1;
    v0.x = acc[i][0]; v0.y = acc[i][1]; v0.z = acc[i][2]; v0.w = acc[i][3];
    v1.x = acc[i][4]; v1.y = acc[i][5]; v1.z = acc[i][6]; v1.w = acc[i][7];
    *(float4*)&Cb[(size_t)m*ldc + n0 + tn*4]      = v0;
    *(float4*)&Cb[(size_t)m*ldc + n0 + 64 + tn*4] = v1;
  }
}

// ---------------- MFMA pd GEMM: 128x128 tile, 16x16x32 bf16, exact 6-seg 3-split ----------------
// pd[m][n] = 2*(HH+HM+MH+MM+HL+LH) - xx[m] - xx[n]  (error ~2^-25, below fp32 product rounding)
__global__ __launch_bounds__(256)
void k_mgemm_pd(const bf16* __restrict__ Xhi, const bf16* __restrict__ Xmd,
                const bf16* __restrict__ Xlo, int lda, long sA,
                float* __restrict__ Cm, int ldc, long sC, int Kseg,
                const float* __restrict__ xx, long sX){
  __shared__ __align__(16) bf16 As[128*32];
  __shared__ __align__(16) bf16 Bs[128*32];
  const int z = blockIdx.z;
  const int m0 = blockIdx.x*128, n0 = blockIdx.y*128;
  const int t = threadIdx.x;
  const int w = t >> 6, lane = t & 63;
  const int wm = w >> 1, wn = w & 1;
  const int quad = lane >> 4, l16 = lane & 15;
  const int srow = lane >> 2, scol = (lane & 3)*8;
  f32x4 acc[4][4];
  #pragma unroll
  for (int i = 0; i < 4; ++i)
    #pragma unroll
    for (int j = 0; j < 4; ++j)
      acc[i][j] = (f32x4){0.f, 0.f, 0.f, 0.f};

  for (int s = 0; s < 6; ++s){
    const bf16* Ab;
    const bf16* Bb;
    switch (s){
      case 0: Ab = Xhi; Bb = Xhi; break;
      case 1: Ab = Xhi; Bb = Xmd; break;
      case 2: Ab = Xmd; Bb = Xhi; break;
      case 3: Ab = Xmd; Bb = Xmd; break;
      case 4: Ab = Xhi; Bb = Xlo; break;
      default:Ab = Xlo; Bb = Xhi; break;
    }
    Ab += (size_t)z*sA;
    Bb += (size_t)z*sA;
    for (int k0 = 0; k0 < Kseg; k0 += 32){
      const bf16* ga0 = Ab + (size_t)(m0 + w*32 + srow)*lda + k0 + scol;
      const bf16* gb0 = Bb + (size_t)(n0 + w*32 + srow)*lda + k0 + scol;
      __syncthreads();
      gload_lds16(ga0,                  &As[(w*32)*32]);
      gload_lds16(ga0 + (size_t)16*lda, &As[(w*32+16)*32]);
      gload_lds16(gb0,                  &Bs[(w*32)*32]);
      gload_lds16(gb0 + (size_t)16*lda, &Bs[(w*32+16)*32]);
      __syncthreads();
      bf16x8 af[4], bfr[4];
      #pragma unroll
      for (int i = 0; i < 4; ++i)
        af[i] = *(const bf16x8*)&As[(wm*64 + i*16 + l16)*32 + quad*8];
      #pragma unroll
      for (int j = 0; j < 4; ++j)
        bfr[j] = *(const bf16x8*)&Bs[(wn*64 + j*16 + l16)*32 + quad*8];
      #pragma unroll
      for (int i = 0; i < 4; ++i)
        #pragma unroll
        for (int j = 0; j < 4; ++j)
          acc[i][j] = __builtin_amdgcn_mfma_f32_16x16x32_bf16(af[i], bfr[j], acc[i][j], 0, 0, 0);
    }
  }
  float* Cb = Cm + (size_t)z*sC;
  const float* xb = xx + (size_t)z*sX;
  #pragma unroll
  for (int j = 0; j < 4; ++j){
    int c = n0 + wn*64 + j*16 + l16;
    float xn = xb[c];
    #pragma unroll
    for (int i = 0; i < 4; ++i){
      int rbase = m0 + wm*64 + i*16 + quad*4;
      #pragma unroll
      for (int r = 0; r < 4; ++r)
        Cb[(size_t)(rbase+r)*ldc + c] = 2.f*acc[i][j][r] - xb[rbase+r] - xn;
    }
  }
}

// ---------------- top-20 per row of pd (chunk of 2 batches). one wave per row ----------------
__global__ __launch_bounds__(256)
void k_topk(const float* __restrict__ pd, int b0, int* __restrict__ idx){
  __shared__ float dist[4][N_];
  const int w = threadIdx.x >> 6, lane = threadIdx.x & 63;
  const int row = blockIdx.x*4 + w;
  const float* prow = pd + (size_t)row * N_;
  float* d = dist[w];
  for (int t = lane; t < N_; t += 64) d[t] = prow[t];
  const int gb = b0 + row / N_;
  const int n = row % N_;
  int* out = idx + ((size_t)gb*N_ + n)*K_;
  for (int t = 0; t < K_; ++t){
    float best = -INFINITY; int bi = N_;
    for (int j = lane; j < N_; j += 64){
      float v = d[j];
      if (v > best || (v == best && j < bi)){ best = v; bi = j; }
    }
    #pragma unroll
    for (int off = 32; off; off >>= 1){
      float ov = __shfl_xor(best, off);
      int oi = __shfl_xor(bi, off);
      if (ov > best || (ov == best && oi < bi)){ best = ov; bi = oi; }
    }
    if (lane == 0){ out[t] = bi; d[bi] = -INFINITY; }
  }
}

// ---------------- gather + max over k + BN stats (R2-verified) ----------------
__global__ __launch_bounds__(256)
void k_edge_assemble(const float* __restrict__ u, const float* __restrict__ v,
                     const int* __restrict__ idx, float* __restrict__ xc,
                     int O, int c0, float* __restrict__ ssum, float* __restrict__ ssq){
  const int tid = threadIdx.x;
  const int npar = 256 / O;
  const int o = tid % O;
  const int slot = tid / O;
  const int nb = N_/64;
  const int b = blockIdx.x / nb, tile = blockIdx.x % nb;
  float lsum = 0.f, lsq = 0.f;
  for (int i = slot; i < 64; i += npar){
    int n = tile*64 + i;
    const float vv = v[((size_t)b*N_+n)*O + o];
    const int* ip = idx + ((size_t)b*N_+n)*K_;
    float m = -INFINITY;
    #pragma unroll
    for (int kk = 0; kk < K_; ++kk){
      int j = ip[kk];
      float h = u[((size_t)b*N_+j)*O + o] + vv;
      m = fmaxf(m, h);
      lsum += h;
      lsq = fmaf(h, h, lsq);
    }
    xc[((size_t)b*N_+n)*512 + c0 + o] = m;
  }
  atomicAdd(&ssum[o], lsum);
  atomicAdd(&ssq[o], lsq);
}

// ---------------- BN scale/shift from stats ----------------
__global__ void k_bn_finalize(const float* __restrict__ ssum, const float* __restrict__ ssq,
                              const float* __restrict__ g, const float* __restrict__ bb,
                              float* __restrict__ sc, float* __restrict__ sh, int O, double cnt){
  int o = threadIdx.x;
  if (o >= O) return;
  double mean = (double)ssum[o] / cnt;
  double var = (double)ssq[o] / cnt - mean*mean;
  if (var < 0.0) var = 0.0;
  float inv = rsqrtf((float)var + EPSV);
  float s = g[o] * inv;
  sc[o] = s;
  sh[o] = bb[o] - (float)mean * s;
}

// ---------------- in-place BN + leaky on xc slice ----------------
__global__ void k_bn_apply(float* __restrict__ xc, int O, int c0,
                           const float* __restrict__ sc, const float* __restrict__ sh){
  int id = blockIdx.x*256 + threadIdx.x;
  if (id >= B_*N_*O) return;
  int o = id % O;
  size_t pn = (size_t)(id / O);
  float* p = &xc[pn*512 + c0 + o];
  float val = fmaf(*p, sc[o], sh[o]);
  *p = leakyf(val);
}

// ---------------- per-channel stats over h5 (B,N,512) ----------------
__global__ void k_h5_stats(const float* __restrict__ h5, float* __restrict__ ssum, float* __restrict__ ssq){
  const int o = threadIdx.x;
  const int nb = N_/64;
  const int b = blockIdx.x / nb, tile = blockIdx.x % nb;
  float ls = 0.f, lq = 0.f;
  for (int i = 0; i < 64; ++i){
    float v = h5[((size_t)b*N_ + tile*64 + i)*512 + o];
    ls += v;
    lq = fmaf(v, v, lq);
  }
  atomicAdd(&ssum[o], ls);
  atomicAdd(&ssq[o], lq);
}

// ---------------- BN+leaky + max/mean over N, two-stage ----------------
__global__ void k_final_partial(const float* __restrict__ h5, const float* __restrict__ sc,
                                const float* __restrict__ sh, float* __restrict__ pmax,
                                float* __restrict__ psum){
  const int o = threadIdx.x;
  const int b = blockIdx.x >> 4, c = blockIdx.x & 15;
  const float s = sc[o], t = sh[o];
  float mx = -INFINITY, sm = 0.f;
  for (int i = 0; i < 128; ++i){
    int n = c*128 + i;
    float v = leakyf(fmaf(h5[((size_t)b*N_+n)*512 + o], s, t));
    mx = fmaxf(mx, v);
    sm += v;
  }
  pmax[(size_t)blockIdx.x*512 + o] = mx;
  psum[(size_t)blockIdx.x*512 + o] = sm;
}

__global__ void k_final_combine(const float* __restrict__ pmax, const float* __restrict__ psum,
                                float* __restrict__ out){
  const int o = threadIdx.x;
  const int b = blockIdx.x;
  float mx = -INFINITY, sm = 0.f;
  for (int c = 0; c < 16; ++c){
    mx = fmaxf(mx, pmax[((size_t)b*16+c)*512 + o]);
    sm += psum[((size_t)b*16+c)*512 + o];
  }
  out[(size_t)b*1024 + o] = mx;
  out[(size_t)b*1024 + 512 + o] = sm * (1.f/N_);
}

extern "C" void kernel_launch(void* const* d_in, const int* in_sizes, int n_in,
                              void* d_out, int out_size, void* d_ws, size_t ws_size,
                              hipStream_t stream){
  const float* x  = (const float*)d_in[0];
  const float* W1 = (const float*)d_in[2];
  const float* g1 = (const float*)d_in[3];
  const float* b1 = (const float*)d_in[4];
  const float* W2 = (const float*)d_in[5];
  const float* g2 = (const float*)d_in[6];
  const float* b2 = (const float*)d_in[7];
  const float* W3 = (const float*)d_in[8];
  const float* g3 = (const float*)d_in[9];
  const float* b3 = (const float*)d_in[10];
  const float* W4 = (const float*)d_in[11];
  const float* g4 = (const float*)d_in[12];
  const float* b4 = (const float*)d_in[13];
  const float* W5 = (const float*)d_in[14];
  const float* g5 = (const float*)d_in[15];
  const float* b5 = (const float*)d_in[16];
  float* out = (float*)d_out;

  // ---- workspace map (float units); ~101 MB ----
  float* w = (float*)d_ws;
  float* xc   = w; w += (size_t)B_*N_*512;     // concat features (b,n,c)
  float* h5b  = w; w += (size_t)B_*N_*512;     // head GEMM out; stage scratch alias
  float* R    = w; w += (size_t)2*N_*N_;       // pd chunk / u_t+v_t / pmax+psum
  float* Wa   = w; w += 256*128;
  float* Wd   = w; w += 256*128;
  float* sc   = w; w += 512;
  float* sh   = w; w += 512;
  float* ssum = w; w += 512;
  float* ssq  = w; w += 512;
  (void)ws_size; (void)in_sizes; (void)n_in; (void)out_size;

  // stage scratch aliased into h5b (dead before the h5 GEMM writes h5b)
  bf16* Xhi  = (bf16*)h5b;                              // 2.097M bf16 max (16384x128)
  bf16* Xmd  = (bf16*)(h5b + 1048576);
  bf16* Xlo  = (bf16*)(h5b + 2097152);
  int*  idxp = (int*)(h5b + 3145728);                   // 16384*20 ints
  float* xx  = h5b + 3145728 + 327680;                  // 16384 f
  float* x0t = h5b + 3145728 + 327680 + 16384;          // (B,N,8) fp32
  // R aliases (time-disjoint)
  float* u_t  = R;
  float* v_t  = R + (size_t)B_*N_*256;
  float* pmax = R;
  float* psum = R + 128*512;

  struct Cfg { int stage1; int c0src; int Cin; int Kp; const float* W; const float* g; const float* bb; int O; int c0; };
  Cfg cfgs[4] = {
    { 1, 0,   3,   32,  W1, g1, b1, 64,  0   },
    { 0, 0,   64,  64,  W2, g2, b2, 64,  64  },
    { 0, 64,  64,  64,  W3, g3, b3, 128, 128 },
    { 0, 128, 128, 128, W4, g4, b4, 256, 256 },
  };

  for (int e = 0; e < 4; ++e){
    Cfg c = cfgs[e];
    if (c.stage1)
      k_prep_x1<<<dim3((B_*N_)/256), dim3(256), 0, stream>>>(x, Xhi, Xmd, Xlo, xx, x0t);
    else
      k_prep_xc<<<dim3((B_*N_)/256), dim3(256), 0, stream>>>(xc + c.c0src, c.Cin, Xhi, Xmd, Xlo, xx);
    k_prep_w<<<dim3((c.O*c.Cin + 255)/256), dim3(256), 0, stream>>>(c.W, Wa, Wd, c.O, c.Cin);
    // pd (MFMA 6-seg exact) + topk, 2 batches per chunk through R
    for (int ch = 0; ch < 4; ++ch){
      int b0 = ch*2;
      k_mgemm_pd<<<dim3(N_/128, N_/128, 2), dim3(256), 0, stream>>>(
        Xhi + (size_t)b0*N_*c.Kp, Xmd + (size_t)b0*N_*c.Kp, Xlo + (size_t)b0*N_*c.Kp,
        c.Kp, (long)N_*c.Kp, R, N_, (long)N_*N_, c.Kp, xx + b0*N_, (long)N_);
      k_topk<<<dim3((2*N_)/4), dim3(256), 0, stream>>>(R, b0, idxp);
    }
    // u/v fp32 GEMMs (R2-verified path)
    const float* Xin = c.stage1 ? x0t : (xc + c.c0src);
    int lda = c.stage1 ? 8 : 512;
    if (c.O >= 128){
      k_gemm128<<<dim3(N_/GBM, c.O/GBN, B_), dim3(256), 0, stream>>>(
        Xin, lda, (long)N_*lda, Wa, c.Cin, 0L, u_t, c.O, (long)N_*c.O, c.Cin);
      k_gemm128<<<dim3(N_/GBM, c.O/GBN, B_), dim3(256), 0, stream>>>(
        Xin, lda, (long)N_*lda, Wd, c.Cin, 0L, v_t, c.O, (long)N_*c.O, c.Cin);
    } else {
      k_gemm_nt<<<dim3(N_/BM, c.O/BN, B_), dim3(256), 0, stream>>>(
        Xin, lda, (long)N_*lda, Wa, c.Cin, 0L, u_t, c.O, (long)N_*c.O, c.Cin);
      k_gemm_nt<<<dim3(N_/BM, c.O/BN, B_), dim3(256), 0, stream>>>(
        Xin, lda, (long)N_*lda, Wd, c.Cin, 0L, v_t, c.O, (long)N_*c.O, c.Cin);
    }
    hipMemsetAsync(ssum, 0, 512*sizeof(float), stream);
    hipMemsetAsync(ssq, 0, 512*sizeof(float), stream);
    k_edge_assemble<<<dim3(B_*(N_/64)), dim3(256), 0, stream>>>(u_t, v_t, idxp, xc, c.O, c.c0, ssum, ssq);
    k_bn_finalize<<<dim3(1), dim3(512), 0, stream>>>(ssum, ssq, c.g, c.bb, sc, sh, c.O, (double)B_*N_*K_);
    k_bn_apply<<<dim3((B_*N_*c.O)/256), dim3(256), 0, stream>>>(xc, c.O, c.c0, sc, sh);
  }

  // head: h5 = xc . W5^T (fp32), BN stats, finalize, pool
  k_gemm128<<<dim3(N_/GBM, 512/GBN, B_), dim3(256), 0, stream>>>(
    xc, 512, (long)N_*512, W5, 512, 0L, h5b, 512, (long)N_*512, 512);
  hipMemsetAsync(ssum, 0, 512*sizeof(float), stream);
  hipMemsetAsync(ssq, 0, 512*sizeof(float), stream);
  k_h5_stats<<<dim3(B_*(N_/64)), dim3(512), 0, stream>>>(h5b, ssum, ssq);
  k_bn_finalize<<<dim3(1), dim3(512), 0, stream>>>(ssum, ssq, g5, b5, sc, sh, 512, (double)B_*N_);
  k_final_partial<<<dim3(B_*16), dim3(512), 0, stream>>>(h5b, sc, sh, pmax, psum);
  k_final_combine<<<dim3(B_), dim3(512), 0, stream>>>(pmax, psum, out);
}